// Round 1
// baseline (170.915 us; speedup 1.0000x reference)
//
#include <hip/hip_runtime.h>
#include <hip/hip_bf16.h>
#include <cstdint>

typedef __bf16 bf16;
typedef __bf16 bf16x4 __attribute__((ext_vector_type(4)));
typedef __bf16 bf16x8 __attribute__((ext_vector_type(8)));
typedef float floatx4 __attribute__((ext_vector_type(4)));

typedef __attribute__((address_space(1))) void as1_void;
typedef __attribute__((address_space(3))) void as3_void;

// async global->LDS, 16B per lane. LDS dest must be wave-uniform base + lane*16
// (our chunk layout guarantees lane i's pointer == base + i*16).
__device__ __forceinline__ void gld16(const void* g, void* l) {
#if __has_builtin(__builtin_amdgcn_global_load_lds)
  __builtin_amdgcn_global_load_lds((as1_void*)(uintptr_t)g, (as3_void*)l, 16, 0, 0);
#else
  *(uint4*)l = *(const uint4*)g;
#endif
}

// ---------------- fp32 -> bf16 conversion (x, Wq|Wk|Wv concat, Wo) -------------
__global__ __launch_bounds__(256) void convert_kernel(
    const float* __restrict__ x, const float* __restrict__ wq,
    const float* __restrict__ wk, const float* __restrict__ wv,
    const float* __restrict__ wo, bf16* __restrict__ xbf,
    bf16* __restrict__ wqkv, bf16* __restrict__ wob) {
  int i = blockIdx.x * 256 + threadIdx.x;  // one float4 (4 elems) per thread
  const float* src;
  bf16* dst;
  int off;
  if (i < 1048576) {            // x: 4,194,304 elems
    src = x; dst = xbf; off = i;
  } else if (i < 1310720) {     // Wq
    src = wq; dst = wqkv; off = i - 1048576;
  } else if (i < 1572864) {     // Wk
    src = wk; dst = wqkv + 1048576; off = i - 1310720;
  } else if (i < 1835008) {     // Wv
    src = wv; dst = wqkv + 2097152; off = i - 1572864;
  } else {                      // Wo
    src = wo; dst = wob; off = i - 1835008;
  }
  float4 v = ((const float4*)src)[off];
  bf16x4 o;
  o[0] = (bf16)v.x; o[1] = (bf16)v.y; o[2] = (bf16)v.z; o[3] = (bf16)v.w;
  ((bf16x4*)dst)[off] = o;
}

// ---------------- NT GEMM: C[M,N] = A[M,K] @ B[N,K]^T  (all K-contiguous) ------
// 128x128 tile, BK=32, 256 threads = 2x2 waves, each wave 64x64 (4x4 MFMA tiles)
// MODE 0: bf16 C out.  MODE 1: fp32 C out + bias.
template <int MODE>
__global__ __launch_bounds__(256) void gemm_nt(const bf16* __restrict__ A,
                                               const bf16* __restrict__ Bm,
                                               bf16* __restrict__ Cb,
                                               float* __restrict__ Cf,
                                               const float* __restrict__ bias,
                                               int M, int N, int K) {
  __shared__ __attribute__((aligned(16))) bf16 As[128 * 32];
  __shared__ __attribute__((aligned(16))) bf16 Bs[128 * 32];
  const int tid = threadIdx.x;
  const int lane = tid & 63;
  const int wave = tid >> 6;
  const int quad = lane >> 4;
  const int n0 = lane & 15;
  const int wm = wave >> 1;
  const int wn = wave & 1;
  const int bN = blockIdx.x, bM = blockIdx.y;
  const bf16* Ab = A + (size_t)bM * 128 * K;
  const bf16* Bb = Bm + (size_t)bN * 128 * K;
  // staging chunks: 512 x 16B per matrix; chunk = (row<<2)|kgroup; LDS byte off = chunk*16
  const int c0 = tid, c1 = tid + 256;
  const int r0 = c0 >> 2, g0 = c0 & 3;
  const int r1 = c1 >> 2, g1 = c1 & 3;
  floatx4 acc[4][4] = {};
  for (int k0 = 0; k0 < K; k0 += 32) {
    gld16(Ab + (size_t)r0 * K + k0 + g0 * 8, &As[c0 * 8]);
    gld16(Ab + (size_t)r1 * K + k0 + g1 * 8, &As[c1 * 8]);
    gld16(Bb + (size_t)r0 * K + k0 + g0 * 8, &Bs[c0 * 8]);
    gld16(Bb + (size_t)r1 * K + k0 + g1 * 8, &Bs[c1 * 8]);
    __syncthreads();  // drains vmcnt(0) before barrier (compiler-emitted)
    bf16x8 af[4], bfr[4];
#pragma unroll
    for (int mi = 0; mi < 4; ++mi)
      af[mi] = *(const bf16x8*)&As[(wm * 64 + mi * 16 + n0) * 32 + quad * 8];
#pragma unroll
    for (int ni = 0; ni < 4; ++ni)
      bfr[ni] = *(const bf16x8*)&Bs[(wn * 64 + ni * 16 + n0) * 32 + quad * 8];
#pragma unroll
    for (int mi = 0; mi < 4; ++mi)
#pragma unroll
      for (int ni = 0; ni < 4; ++ni)
        acc[mi][ni] = __builtin_amdgcn_mfma_f32_16x16x32_bf16(
            af[mi], bfr[ni], acc[mi][ni], 0, 0, 0);
    __syncthreads();
  }
  // epilogue: D elem (row = quad*4+reg, col = lane&15) within each 16x16 tile
  const int rowBase = bM * 128 + wm * 64;
  const int colBase = bN * 128 + wn * 64;
#pragma unroll
  for (int ni = 0; ni < 4; ++ni) {
    const int col = colBase + ni * 16 + n0;
    float badd = 0.f;
    if (MODE == 1) badd = bias[col];
#pragma unroll
    for (int mi = 0; mi < 4; ++mi)
#pragma unroll
      for (int r = 0; r < 4; ++r) {
        const int row = rowBase + mi * 16 + quad * 4 + r;
        if (MODE == 0)
          Cb[(size_t)row * N + col] = (bf16)acc[mi][ni][r];
        else
          Cf[(size_t)row * N + col] = acc[mi][ni][r] + badd;
      }
  }
}

// ---------------- sliding-window attention ------------------------------------
// block = (b, h, 64-query tile); 4 waves, wave w owns queries [w*16, w*16+16).
// Key window: 128 rows t=0..127 <-> j = i0-32+t; out-of-range rows loaded as 0
// (=> score 0, matching the reference's zero-padded K; V row 0 contributes 0).
// Band mask: query q64 attends t in [q64, q64+64).
__global__ __launch_bounds__(256) void attn_kernel(const bf16* __restrict__ qkv,
                                                   bf16* __restrict__ aout) {
  __shared__ __attribute__((aligned(16))) bf16 Qs[64 * 64];
  __shared__ __attribute__((aligned(16))) bf16 Ks[128 * 64];
  __shared__ __attribute__((aligned(16))) bf16 Vs[128 * 64];
  __shared__ __attribute__((aligned(16))) bf16 Ps[4 * 16 * 128];
  const int bid = blockIdx.x;
  const int b = bid >> 9;            // 512 blocks per batch (16 heads x 32 tiles)
  const int h = (bid >> 5) & 15;
  const int i0 = (bid & 31) * 64;
  const int tid = threadIdx.x;
  const int wave = tid >> 6, lane = tid & 63;
  const int quad = lane >> 4, n0 = lane & 15;

  // Q tile: 64 rows x 64 cols (8x 16B chunks per row)
  for (int idx = tid; idx < 512; idx += 256) {
    const int r = idx >> 3, c = idx & 7;
    *(uint4*)&Qs[r * 64 + c * 8] =
        *(const uint4*)(qkv + (size_t)(b * 2048 + i0 + r) * 3072 + h * 64 + c * 8);
  }
  // K and V windows: 128 rows x 8 chunks each
  for (int idx = tid; idx < 2048; idx += 256) {
    const int kv = idx >> 10;
    const int r = (idx >> 3) & 127, c = idx & 7;
    const int j = i0 - 32 + r;
    uint4 val = make_uint4(0u, 0u, 0u, 0u);
    if (j >= 0 && j < 2048)
      val = *(const uint4*)(qkv + (size_t)(b * 2048 + j) * 3072 + 1024 +
                            kv * 1024 + h * 64 + c * 8);
    bf16* dst = kv ? Vs : Ks;
    *(uint4*)&dst[r * 64 + c * 8] = val;
  }
  __syncthreads();

  // S = Q(16x64) @ Kwin(128x64)^T : 8 n-tiles x 2 k-steps
  bf16x8 aq[2];
#pragma unroll
  for (int ks = 0; ks < 2; ++ks)
    aq[ks] = *(const bf16x8*)&Qs[(wave * 16 + n0) * 64 + ks * 32 + quad * 8];
  floatx4 accS[8] = {};
#pragma unroll
  for (int nt = 0; nt < 8; ++nt)
#pragma unroll
    for (int ks = 0; ks < 2; ++ks) {
      bf16x8 bk = *(const bf16x8*)&Ks[(nt * 16 + n0) * 64 + ks * 32 + quad * 8];
      accS[nt] = __builtin_amdgcn_mfma_f32_16x16x32_bf16(aq[ks], bk, accS[nt], 0, 0, 0);
    }

  // scale + band mask + softmax (rows live across the 16 lanes of a quad)
  float mrow[4] = {-1e30f, -1e30f, -1e30f, -1e30f};
#pragma unroll
  for (int nt = 0; nt < 8; ++nt)
#pragma unroll
    for (int r = 0; r < 4; ++r) {
      const int q64 = wave * 16 + quad * 4 + r;
      const int t = nt * 16 + n0;
      float s = accS[nt][r] * 0.125f;  // 1/sqrt(64)
      if (t < q64 || t >= q64 + 64) s = -1e30f;
      accS[nt][r] = s;
      mrow[r] = fmaxf(mrow[r], s);
    }
#pragma unroll
  for (int off = 1; off < 16; off <<= 1)
#pragma unroll
    for (int r = 0; r < 4; ++r)
      mrow[r] = fmaxf(mrow[r], __shfl_xor(mrow[r], off));
  float lrow[4] = {0.f, 0.f, 0.f, 0.f};
#pragma unroll
  for (int nt = 0; nt < 8; ++nt)
#pragma unroll
    for (int r = 0; r < 4; ++r) {
      const float e = __expf(accS[nt][r] - mrow[r]);
      accS[nt][r] = e;
      lrow[r] += e;
    }
#pragma unroll
  for (int off = 1; off < 16; off <<= 1)
#pragma unroll
    for (int r = 0; r < 4; ++r) lrow[r] += __shfl_xor(lrow[r], off);

  // P (C-layout) -> LDS -> A-layout (per-wave private region, no barrier needed)
  bf16* Pw = &Ps[wave * 2048];
#pragma unroll
  for (int r = 0; r < 4; ++r) {
    const float inv = 1.f / lrow[r];
#pragma unroll
    for (int nt = 0; nt < 8; ++nt)
      Pw[(quad * 4 + r) * 128 + nt * 16 + n0] = (bf16)(accS[nt][r] * inv);
  }

  // O = P(16x128) @ V(128x64): 4 k-steps x 4 d-tiles
  floatx4 accO[4] = {};
#pragma unroll
  for (int kt = 0; kt < 4; ++kt) {
    bf16x8 ap = *(const bf16x8*)&Pw[n0 * 128 + kt * 32 + quad * 8];
#pragma unroll
    for (int dt = 0; dt < 4; ++dt) {
      bf16x8 bv;  // B[n=d][k=t] = V[t][d] (strided scalar LDS reads)
#pragma unroll
      for (int jj = 0; jj < 8; ++jj)
        bv[jj] = Vs[(kt * 32 + quad * 8 + jj) * 64 + dt * 16 + n0];
      accO[dt] = __builtin_amdgcn_mfma_f32_16x16x32_bf16(ap, bv, accO[dt], 0, 0, 0);
    }
  }
#pragma unroll
  for (int dt = 0; dt < 4; ++dt)
#pragma unroll
    for (int r = 0; r < 4; ++r) {
      const int q64 = wave * 16 + quad * 4 + r;
      aout[(size_t)(b * 2048 + i0 + q64) * 1024 + h * 64 + dt * 16 + n0] =
          (bf16)accO[dt][r];
    }
}

// ---------------- launch -------------------------------------------------------
// ws layout (40 MB total):
//   [0,   8MB) xbf (4096x1024 bf16)   -- reused as attnout after GEMM1
//   [8,  14MB) wqkv bf16 (3072x1024, rows = [Wq;Wk;Wv])
//   [14, 16MB) wob  bf16 (1024x1024)
//   [16, 40MB) qkv  bf16 (4096x3072, row = [Q|K|V])
extern "C" void kernel_launch(void* const* d_in, const int* in_sizes, int n_in,
                              void* d_out, int out_size, void* d_ws, size_t ws_size,
                              hipStream_t stream) {
  const float* x = (const float*)d_in[0];
  const float* wq = (const float*)d_in[1];
  const float* wk = (const float*)d_in[2];
  const float* wv = (const float*)d_in[3];
  const float* wo = (const float*)d_in[4];
  const float* bo = (const float*)d_in[5];
  char* ws = (char*)d_ws;
  bf16* xbf = (bf16*)(ws);
  bf16* wqkv = (bf16*)(ws + (8u << 20));
  bf16* wob = (bf16*)(ws + (14u << 20));
  bf16* qkv = (bf16*)(ws + (16u << 20));
  bf16* aout = xbf;  // xbf dead after GEMM1; stream-ordered reuse

  convert_kernel<<<8192, 256, 0, stream>>>(x, wq, wk, wv, wo, xbf, wqkv, wob);
  // QKV projection: (4096 x 3072) = xbf(4096x1024) @ wqkv^T
  gemm_nt<0><<<dim3(24, 32), 256, 0, stream>>>(xbf, wqkv, qkv, nullptr, nullptr,
                                               4096, 3072, 1024);
  attn_kernel<<<1024, 256, 0, stream>>>(qkv, aout);
  // output projection: (4096 x 1024) fp32 = aout @ wob^T + bo
  gemm_nt<1><<<dim3(8, 32), 256, 0, stream>>>(aout, wob, nullptr, (float*)d_out,
                                              bo, 4096, 1024, 1024);
}

// Round 2
// 157.818 us; speedup vs baseline: 1.0830x; 1.0830x over previous
//
#include <hip/hip_runtime.h>
#include <hip/hip_bf16.h>
#include <cstdint>

typedef __bf16 bf16;
typedef __bf16 bf16x4 __attribute__((ext_vector_type(4)));
typedef __bf16 bf16x8 __attribute__((ext_vector_type(8)));
typedef float floatx4 __attribute__((ext_vector_type(4)));

typedef __attribute__((address_space(1))) void as1_void;
typedef __attribute__((address_space(3))) void as3_void;

// async global->LDS, 16B per lane. LDS dest must be wave-uniform base + lane*16.
__device__ __forceinline__ void gld16(const void* g, void* l) {
#if __has_builtin(__builtin_amdgcn_global_load_lds)
  __builtin_amdgcn_global_load_lds((as1_void*)(uintptr_t)g, (as3_void*)l, 16, 0, 0);
#else
  *(uint4*)l = *(const uint4*)g;
#endif
}

// ---------------- fp32 -> bf16 conversion (x, Wq|Wk|Wv concat, Wo) -------------
__global__ __launch_bounds__(256) void convert_kernel(
    const float* __restrict__ x, const float* __restrict__ wq,
    const float* __restrict__ wk, const float* __restrict__ wv,
    const float* __restrict__ wo, bf16* __restrict__ xbf,
    bf16* __restrict__ wqkv, bf16* __restrict__ wob) {
  int i = blockIdx.x * 256 + threadIdx.x;  // one float4 (4 elems) per thread
  const float* src;
  bf16* dst;
  int off;
  if (i < 1048576) {            // x: 4,194,304 elems
    src = x; dst = xbf; off = i;
  } else if (i < 1310720) {     // Wq
    src = wq; dst = wqkv; off = i - 1048576;
  } else if (i < 1572864) {     // Wk
    src = wk; dst = wqkv + 1048576; off = i - 1310720;
  } else if (i < 1835008) {     // Wv
    src = wv; dst = wqkv + 2097152; off = i - 1572864;
  } else {                      // Wo
    src = wo; dst = wob; off = i - 1835008;
  }
  float4 v = ((const float4*)src)[off];
  bf16x4 o;
  o[0] = (bf16)v.x; o[1] = (bf16)v.y; o[2] = (bf16)v.z; o[3] = (bf16)v.w;
  ((bf16x4*)dst)[off] = o;
}

// ---------------- NT GEMM: C[M,N] = A[M,K] @ B[N,K]^T --------------------------
// 128 x BN tile, BK=32, 256 threads = 2x2 waves; wave tile 64 x BN/2.
// MODE 0: bf16 C out.  MODE 1: fp32 C out + bias.
template <int MODE, int BN>
__global__ __launch_bounds__(256) void gemm_nt(const bf16* __restrict__ A,
                                               const bf16* __restrict__ Bm,
                                               bf16* __restrict__ Cb,
                                               float* __restrict__ Cf,
                                               const float* __restrict__ bias,
                                               int M, int N, int K) {
  constexpr int WN = BN / 2;       // wave n-extent
  constexpr int NI = WN / 16;      // n-tiles per wave
  __shared__ __attribute__((aligned(16))) bf16 As[128 * 32];
  __shared__ __attribute__((aligned(16))) bf16 Bs[BN * 32];
  const int tid = threadIdx.x;
  const int lane = tid & 63;
  const int wave = tid >> 6;
  const int quad = lane >> 4;
  const int n0 = lane & 15;
  const int wm = wave >> 1;
  const int wn = wave & 1;
  const int bN = blockIdx.x, bM = blockIdx.y;
  const bf16* Ab = A + (size_t)bM * 128 * K;
  const bf16* Bb = Bm + (size_t)bN * BN * K;
  const int c0 = tid, c1 = tid + 256;
  floatx4 acc[4][NI] = {};
  for (int k0 = 0; k0 < K; k0 += 32) {
    gld16(Ab + (size_t)(c0 >> 2) * K + k0 + (c0 & 3) * 8, &As[c0 * 8]);
    gld16(Ab + (size_t)(c1 >> 2) * K + k0 + (c1 & 3) * 8, &As[c1 * 8]);
#pragma unroll
    for (int cc = 0; cc < BN * 4; cc += 256) {
      const int c = cc + tid;
      gld16(Bb + (size_t)(c >> 2) * K + k0 + (c & 3) * 8, &Bs[c * 8]);
    }
    __syncthreads();
    bf16x8 af[4], bfr[NI];
#pragma unroll
    for (int mi = 0; mi < 4; ++mi)
      af[mi] = *(const bf16x8*)&As[(wm * 64 + mi * 16 + n0) * 32 + quad * 8];
#pragma unroll
    for (int ni = 0; ni < NI; ++ni)
      bfr[ni] = *(const bf16x8*)&Bs[(wn * WN + ni * 16 + n0) * 32 + quad * 8];
#pragma unroll
    for (int mi = 0; mi < 4; ++mi)
#pragma unroll
      for (int ni = 0; ni < NI; ++ni)
        acc[mi][ni] = __builtin_amdgcn_mfma_f32_16x16x32_bf16(
            af[mi], bfr[ni], acc[mi][ni], 0, 0, 0);
    __syncthreads();
  }
  const int rowBase = bM * 128 + wm * 64;
  const int colBase = bN * BN + wn * WN;
#pragma unroll
  for (int ni = 0; ni < NI; ++ni) {
    const int col = colBase + ni * 16 + n0;
    float badd = 0.f;
    if (MODE == 1) badd = bias[col];
#pragma unroll
    for (int mi = 0; mi < 4; ++mi)
#pragma unroll
      for (int r = 0; r < 4; ++r) {
        const int row = rowBase + mi * 16 + quad * 4 + r;
        if (MODE == 0)
          Cb[(size_t)row * N + col] = (bf16)acc[mi][ni][r];
        else
          Cf[(size_t)row * N + col] = acc[mi][ni][r] + badd;
      }
  }
}

// ---------------- sliding-window attention ------------------------------------
// block = (b, h, 64-query tile); 4 waves, wave w owns queries [w*16, w*16+16).
// Key window rows t=0..127 <-> j = i0-32+t; out-of-range rows are zero
// (matches reference zero-padding: score 0 participates in softmax, V adds 0).
// LDS strides chosen so every frag access is <=2 lanes/bank (free, m136):
//   Ks stride 72 (144 B), Vt stride 136 (272 B), Ps stride 136.
__global__ __launch_bounds__(256) void attn_kernel(const bf16* __restrict__ qkv,
                                                   bf16* __restrict__ aout) {
  __shared__ __attribute__((aligned(16))) bf16 Ks[128 * 72];
  __shared__ __attribute__((aligned(16))) bf16 VsPs[128 * 72];  // Vs, then Ps
  __shared__ __attribute__((aligned(16))) bf16 Vt[64 * 136];
  const int bid = blockIdx.x;
  const int b = bid >> 9;            // 512 blocks per batch (16 heads x 32 tiles)
  const int h = (bid >> 5) & 15;
  const int i0 = (bid & 31) * 64;
  const int tid = threadIdx.x;
  const int wave = tid >> 6, lane = tid & 63;
  const int quad = lane >> 4, n0 = lane & 15;
  bf16* Vs = VsPs;

  // stage K and V windows: 128 rows x 8 16B-chunks each, zero out-of-range
#pragma unroll
  for (int it = 0; it < 4; ++it) {
    const int idx = it * 256 + tid;
    const int r = idx >> 3, c = idx & 7;
    const int j = i0 - 32 + r;
    uint4 kv_ = make_uint4(0u, 0u, 0u, 0u);
    uint4 vv = make_uint4(0u, 0u, 0u, 0u);
    if (j >= 0 && j < 2048) {
      const bf16* base = qkv + (size_t)(b * 2048 + j) * 3072 + 1024 + h * 64 + c * 8;
      kv_ = *(const uint4*)base;
      vv = *(const uint4*)(base + 1024);
    }
    *(uint4*)&Ks[r * 72 + c * 8] = kv_;
    *(uint4*)&Vs[r * 72 + c * 8] = vv;
  }
  __syncthreads();

  // transpose V: Vs[t][d] -> Vt[d][t]  (reads uniform b128, writes 2-lane/bank)
#pragma unroll
  for (int it = 0; it < 4; ++it) {
    const int idx = it * 256 + tid;
    const int t = idx & 127, c = idx >> 7;
    bf16x8 v = *(const bf16x8*)&Vs[t * 72 + c * 8];
#pragma unroll
    for (int jj = 0; jj < 8; ++jj) Vt[(c * 8 + jj) * 136 + t] = v[jj];
  }
  __syncthreads();

  // Q fragments straight from global (each lane's frag is one contiguous 16B)
  bf16x8 aq[2];
#pragma unroll
  for (int ks = 0; ks < 2; ++ks)
    aq[ks] = *(const bf16x8*)(qkv +
        (size_t)(b * 2048 + i0 + wave * 16 + n0) * 3072 + h * 64 + ks * 32 + quad * 8);

  // S = Q(16x64) @ Kwin(128x64)^T : 8 n-tiles x 2 k-steps
  floatx4 accS[8] = {};
#pragma unroll
  for (int nt = 0; nt < 8; ++nt)
#pragma unroll
    for (int ks = 0; ks < 2; ++ks) {
      bf16x8 bk = *(const bf16x8*)&Ks[(nt * 16 + n0) * 72 + ks * 32 + quad * 8];
      accS[nt] = __builtin_amdgcn_mfma_f32_16x16x32_bf16(aq[ks], bk, accS[nt], 0, 0, 0);
    }

  // scale + band mask + softmax (rows live across the 16 lanes of a quad)
  float mrow[4] = {-1e30f, -1e30f, -1e30f, -1e30f};
#pragma unroll
  for (int nt = 0; nt < 8; ++nt)
#pragma unroll
    for (int r = 0; r < 4; ++r) {
      const int q64 = wave * 16 + quad * 4 + r;
      const int t = nt * 16 + n0;
      float s = accS[nt][r] * 0.125f;  // 1/sqrt(64)
      if (t < q64 || t >= q64 + 64) s = -1e30f;
      accS[nt][r] = s;
      mrow[r] = fmaxf(mrow[r], s);
    }
#pragma unroll
  for (int off = 1; off < 16; off <<= 1)
#pragma unroll
    for (int r = 0; r < 4; ++r)
      mrow[r] = fmaxf(mrow[r], __shfl_xor(mrow[r], off));
  float lrow[4] = {0.f, 0.f, 0.f, 0.f};
#pragma unroll
  for (int nt = 0; nt < 8; ++nt)
#pragma unroll
    for (int r = 0; r < 4; ++r) {
      const float e = __expf(accS[nt][r] - mrow[r]);
      accS[nt][r] = e;
      lrow[r] += e;
    }
#pragma unroll
  for (int off = 1; off < 16; off <<= 1)
#pragma unroll
    for (int r = 0; r < 4; ++r) lrow[r] += __shfl_xor(lrow[r], off);

  // P (C-layout) -> LDS A-layout; per-wave region of VsPs (Vs dead after barrier)
  bf16* Pw = &VsPs[wave * 16 * 136];
#pragma unroll
  for (int r = 0; r < 4; ++r) {
    const float inv = 1.f / lrow[r];
#pragma unroll
    for (int nt = 0; nt < 8; ++nt)
      Pw[(quad * 4 + r) * 136 + nt * 16 + n0] = (bf16)(accS[nt][r] * inv);
  }

  // O = P(16x128) @ V(128x64): 4 k-steps x 4 d-tiles, all b128 frag reads
  floatx4 accO[4] = {};
#pragma unroll
  for (int kt = 0; kt < 4; ++kt) {
    bf16x8 ap = *(const bf16x8*)&Pw[n0 * 136 + kt * 32 + quad * 8];
#pragma unroll
    for (int dt = 0; dt < 4; ++dt) {
      bf16x8 bv = *(const bf16x8*)&Vt[(dt * 16 + n0) * 136 + kt * 32 + quad * 8];
      accO[dt] = __builtin_amdgcn_mfma_f32_16x16x32_bf16(ap, bv, accO[dt], 0, 0, 0);
    }
  }
#pragma unroll
  for (int dt = 0; dt < 4; ++dt)
#pragma unroll
    for (int r = 0; r < 4; ++r) {
      const int q64 = wave * 16 + quad * 4 + r;
      aout[(size_t)(b * 2048 + i0 + q64) * 1024 + h * 64 + dt * 16 + n0] =
          (bf16)accO[dt][r];
    }
}

// ---------------- launch -------------------------------------------------------
// ws layout (40 MB total):
//   [0,   8MB) xbf (4096x1024 bf16)   -- reused as attnout after GEMM1
//   [8,  14MB) wqkv bf16 (3072x1024, rows = [Wq;Wk;Wv])
//   [14, 16MB) wob  bf16 (1024x1024)
//   [16, 40MB) qkv  bf16 (4096x3072, row = [Q|K|V])
extern "C" void kernel_launch(void* const* d_in, const int* in_sizes, int n_in,
                              void* d_out, int out_size, void* d_ws, size_t ws_size,
                              hipStream_t stream) {
  const float* x = (const float*)d_in[0];
  const float* wq = (const float*)d_in[1];
  const float* wk = (const float*)d_in[2];
  const float* wv = (const float*)d_in[3];
  const float* wo = (const float*)d_in[4];
  const float* bo = (const float*)d_in[5];
  char* ws = (char*)d_ws;
  bf16* xbf = (bf16*)(ws);
  bf16* wqkv = (bf16*)(ws + (8u << 20));
  bf16* wob = (bf16*)(ws + (14u << 20));
  bf16* qkv = (bf16*)(ws + (16u << 20));
  bf16* aout = xbf;  // xbf dead after GEMM1; stream-ordered reuse

  convert_kernel<<<8192, 256, 0, stream>>>(x, wq, wk, wv, wo, xbf, wqkv, wob);
  // QKV projection: (4096 x 3072) = xbf(4096x1024) @ wqkv^T
  gemm_nt<0, 128><<<dim3(24, 32), 256, 0, stream>>>(xbf, wqkv, qkv, nullptr,
                                                    nullptr, 4096, 3072, 1024);
  attn_kernel<<<1024, 256, 0, stream>>>(qkv, aout);
  // output projection: (4096 x 1024) fp32 = aout @ wob^T + bo, 512 blocks
  gemm_nt<1, 64><<<dim3(16, 32), 256, 0, stream>>>(aout, wob, nullptr,
                                                   (float*)d_out, bo, 4096, 1024,
                                                   1024);
}